// Round 1
// baseline (7660.758 us; speedup 1.0000x reference)
//
#include <hip/hip_runtime.h>
#include <stdint.h>

typedef _Float16 f16;
typedef _Float16 f16x8 __attribute__((ext_vector_type(8)));
typedef float f32x4 __attribute__((ext_vector_type(4)));

#define MFMA16(a, b, c) __builtin_amdgcn_mfma_f32_16x16x32_f16((a), (b), (c), 0, 0, 0)

// Sizes (fixed for this problem)
// B=64, S=512, I=512, H=1024, 4H=4096, O=64

// ---------------- prep kernels ----------------

// x (B,S,I) f32 -> x16 (S,B,I) f16   (step-major so each step's A-tile is contiguous)
__global__ void k_conv_x(const float* __restrict__ x, f16* __restrict__ x16) {
  int s = blockIdx.x >> 6, b = blockIdx.x & 63;
  const float4* src = (const float4*)(x + ((size_t)b * 512 + s) * 512);
  f16* dst = x16 + (size_t)blockIdx.x * 512;
  int tid = threadIdx.x;
  float4 v = src[tid];
  union { f16 h[4]; uint64_t u; } tmp;
  tmp.h[0] = (f16)v.x; tmp.h[1] = (f16)v.y; tmp.h[2] = (f16)v.z; tmp.h[3] = (f16)v.w;
  *(uint64_t*)(dst + tid * 4) = tmp.u;
}

// Weight reorder + f32->f16.  Dest row d (0..4095): jb=d>>5, r=d&31, q=r>>3, jl=r&7,
// source gate row g = q*1024 + jb*8 + jl.  Row = [Wih(g,0..KI) | Whh(g,0..1024)].
// So block jb's 32 consecutive rows hold all 4 gates for its 8 h-columns.
__global__ void k_conv_w(const float* __restrict__ Wih, const float* __restrict__ Whh,
                         const float* __restrict__ bih, const float* __restrict__ bhh,
                         f16* __restrict__ Wr, float* __restrict__ br, int KI) {
  int d = blockIdx.x;
  int jb = d >> 5, r = d & 31, q = r >> 3, jl = r & 7;
  int g = q * 1024 + jb * 8 + jl;
  int Ktot = KI + 1024;
  const float* src0 = Wih + (size_t)g * KI;
  const float* src1 = Whh + (size_t)g * 1024;
  f16* dst = Wr + (size_t)d * Ktot;
  for (int k = threadIdx.x; k < Ktot; k += blockDim.x) {
    float v = (k < KI) ? src0[k] : src1[k - KI];
    dst[k] = (f16)v;
  }
  if (threadIdx.x == 0) br[d] = bih[g] + bhh[g];
}

__global__ void k_conv_wfc(const float* __restrict__ Wfc, f16* __restrict__ Wfc16) {
  int i = blockIdx.x * 256 + threadIdx.x;  // 64*1024 elements
  Wfc16[i] = (f16)Wfc[i];
}

// ---------------- fused pipelined LSTM step ----------------
// Grid: 256 blocks x 512 threads. Blocks 0..127: layer0 step t. Blocks 128..255: layer1 step t-1.
// Each block: C(64 x 32) = A(64 x Ktot) @ Wslab^T, 8 waves K-split, wave tile 64x32,
// all MFMA fragments loaded directly from global (L2-resident), LDS for K-reduction,
// then LSTM pointwise for its 8 h-columns.
__global__ __launch_bounds__(512, 1)
void k_step(const f16* __restrict__ x16,
            const f16* __restrict__ W0r, const float* __restrict__ b0r,
            const f16* __restrict__ W1r, const float* __restrict__ b1r,
            f16* __restrict__ h0b0, f16* __restrict__ h0b1,
            f16* __restrict__ h1b0, f16* __restrict__ h1b1,
            float* __restrict__ c0, float* __restrict__ c1,
            f16* __restrict__ h1all, int t) {
  const int layer = blockIdx.x >> 7;
  const int jb = blockIdx.x & 127;
  if (layer == 0 && t >= 512) return;
  if (layer == 1 && t == 0) return;

  __shared__ float cred[8][64][33];  // padded stride vs bank conflicts

  const f16 *A0, *A1, *Bs;
  const float* bias;
  float* cst;
  f16 *hout, *hall = nullptr;
  int KA, Ktot, ldA0, ldA1;

  if (layer == 0) {
    A0 = x16 + (size_t)t * (64 * 512); ldA0 = 512; KA = 512;
    A1 = (t & 1) ? h0b0 : h0b1;        ldA1 = 1024;   // h0_{t-1}
    Ktot = 1536;
    Bs = W0r + (size_t)jb * 32 * 1536;
    bias = b0r + jb * 32;
    cst = c0;
    hout = (t & 1) ? h0b1 : h0b0;                      // h0_t
  } else {
    const int tau = t - 1;
    A0 = (tau & 1) ? h0b1 : h0b0; ldA0 = 1024; KA = 1024;  // h0_tau
    A1 = (tau & 1) ? h1b0 : h1b1; ldA1 = 1024;             // h1_{tau-1}
    Ktot = 2048;
    Bs = W1r + (size_t)jb * 32 * 2048;
    bias = b1r + jb * 32;
    cst = c1;
    hout = (tau & 1) ? h1b1 : h1b0;                        // h1_tau
    hall = h1all + (size_t)tau * (64 * 1024);
  }

  const int w = threadIdx.x >> 6;
  const int lane = threadIdx.x & 63;
  const int l15 = lane & 15;
  const int ksub = (lane >> 4) << 3;  // element offset within a 32-wide k-step

  f32x4 acc[4][2];
#pragma unroll
  for (int i = 0; i < 4; ++i) {
    acc[i][0] = f32x4{0.f, 0.f, 0.f, 0.f};
    acc[i][1] = f32x4{0.f, 0.f, 0.f, 0.f};
  }

  const int kPer = Ktot >> 3;  // 192 (L0) or 256 (L1), multiple of 64
  const int kbeg = w * kPer, kend = kbeg + kPer;

  f16x8 af0[4], bf0[2], af1[4], bf1[2];

  auto LOADK = [&](int kc, f16x8(&a)[4], f16x8(&b)[2]) {
    const f16* sA; int ld, ko;
    if (kc < KA) { sA = A0; ld = ldA0; ko = kc; }
    else         { sA = A1; ld = ldA1; ko = kc - KA; }
    const f16* ap = sA + ko + ksub;
#pragma unroll
    for (int rf = 0; rf < 4; ++rf)
      a[rf] = *(const f16x8*)(ap + (size_t)(rf * 16 + l15) * ld);
    const f16* bp = Bs + kc + ksub;
#pragma unroll
    for (int cf = 0; cf < 2; ++cf)
      b[cf] = *(const f16x8*)(bp + (size_t)(cf * 16 + l15) * Ktot);
  };

  LOADK(kbeg, af0, bf0);
  for (int kc = kbeg; kc < kend; kc += 64) {
    LOADK(kc + 32, af1, bf1);
#pragma unroll
    for (int rf = 0; rf < 4; ++rf) {
      acc[rf][0] = MFMA16(af0[rf], bf0[0], acc[rf][0]);
      acc[rf][1] = MFMA16(af0[rf], bf0[1], acc[rf][1]);
    }
    if (kc + 64 < kend) LOADK(kc + 64, af0, bf0);
#pragma unroll
    for (int rf = 0; rf < 4; ++rf) {
      acc[rf][0] = MFMA16(af1[rf], bf1[0], acc[rf][0]);
      acc[rf][1] = MFMA16(af1[rf], bf1[1], acc[rf][1]);
    }
  }

  // C/D layout (16x16x32): col = lane&15, row = (lane>>4)*4 + reg  [verified m89]
#pragma unroll
  for (int rf = 0; rf < 4; ++rf)
#pragma unroll
    for (int cf = 0; cf < 2; ++cf)
#pragma unroll
      for (int r = 0; r < 4; ++r)
        cred[w][rf * 16 + (lane >> 4) * 4 + r][cf * 16 + l15] = acc[rf][cf][r];

  __syncthreads();

  // pointwise LSTM: one (m, jl) per thread; gate q lives at local col q*8+jl
  {
    int m = threadIdx.x >> 3, jl = threadIdx.x & 7;
    float ip = 0.f, fp = 0.f, gp = 0.f, op = 0.f;
#pragma unroll
    for (int ww = 0; ww < 8; ++ww) {
      ip += cred[ww][m][jl];
      fp += cred[ww][m][8 + jl];
      gp += cred[ww][m][16 + jl];
      op += cred[ww][m][24 + jl];
    }
    ip += bias[jl]; fp += bias[8 + jl]; gp += bias[16 + jl]; op += bias[24 + jl];
    float ig = 1.f / (1.f + __expf(-ip));
    float fg = 1.f / (1.f + __expf(-fp));
    float gg = tanhf(gp);
    float og = 1.f / (1.f + __expf(-op));
    int jg = jb * 8 + jl;
    size_t idx = (size_t)m * 1024 + jg;
    float cn = fg * cst[idx] + ig * gg;
    cst[idx] = cn;
    float h = og * tanhf(cn);
    hout[idx] = (f16)h;
    if (hall) hall[idx] = (f16)h;
  }
}

// ---------------- final FC: out(b,s,o) = h1(s,b,:) @ Wfc^T + bfc ----------------
__global__ __launch_bounds__(512, 1)
void k_fc(const f16* __restrict__ h1all, const f16* __restrict__ Wfc16,
          const float* __restrict__ bfc, float* __restrict__ out) {
  const int s = blockIdx.x;
  const f16* A = h1all + (size_t)s * (64 * 1024);
  __shared__ float cred[8][64][65];

  const int w = threadIdx.x >> 6;
  const int lane = threadIdx.x & 63;
  const int l15 = lane & 15;
  const int ksub = (lane >> 4) << 3;

  f32x4 acc[4][4];
#pragma unroll
  for (int i = 0; i < 4; ++i)
#pragma unroll
    for (int j = 0; j < 4; ++j) acc[i][j] = f32x4{0.f, 0.f, 0.f, 0.f};

  const int kbeg = w * 128, kend = kbeg + 128;
  f16x8 af0[4], bf0[4], af1[4], bf1[4];

  auto LOADK = [&](int kc, f16x8(&a)[4], f16x8(&b)[4]) {
    const f16* ap = A + kc + ksub;
#pragma unroll
    for (int rf = 0; rf < 4; ++rf)
      a[rf] = *(const f16x8*)(ap + (size_t)(rf * 16 + l15) * 1024);
    const f16* bp = Wfc16 + kc + ksub;
#pragma unroll
    for (int cf = 0; cf < 4; ++cf)
      b[cf] = *(const f16x8*)(bp + (size_t)(cf * 16 + l15) * 1024);
  };

  LOADK(kbeg, af0, bf0);
  for (int kc = kbeg; kc < kend; kc += 64) {
    LOADK(kc + 32, af1, bf1);
#pragma unroll
    for (int rf = 0; rf < 4; ++rf)
#pragma unroll
      for (int cf = 0; cf < 4; ++cf) acc[rf][cf] = MFMA16(af0[rf], bf0[cf], acc[rf][cf]);
    if (kc + 64 < kend) LOADK(kc + 64, af0, bf0);
#pragma unroll
    for (int rf = 0; rf < 4; ++rf)
#pragma unroll
      for (int cf = 0; cf < 4; ++cf) acc[rf][cf] = MFMA16(af1[rf], bf1[cf], acc[rf][cf]);
  }

#pragma unroll
  for (int rf = 0; rf < 4; ++rf)
#pragma unroll
    for (int cf = 0; cf < 4; ++cf)
#pragma unroll
      for (int r = 0; r < 4; ++r)
        cred[w][rf * 16 + (lane >> 4) * 4 + r][cf * 16 + l15] = acc[rf][cf][r];

  __syncthreads();

  int m = threadIdx.x >> 3;           // batch row
  int cbase = (threadIdx.x & 7) * 8;  // 8 output cols per thread
#pragma unroll
  for (int u = 0; u < 8; ++u) {
    int col = cbase + u;
    float v = bfc[col];
#pragma unroll
    for (int ww = 0; ww < 8; ++ww) v += cred[ww][m][col];
    out[((size_t)m * 512 + s) * 64 + col] = v;
  }
}

// ---------------- host ----------------
extern "C" void kernel_launch(void* const* d_in, const int* in_sizes, int n_in,
                              void* d_out, int out_size, void* d_ws, size_t ws_size,
                              hipStream_t stream) {
  const float* x    = (const float*)d_in[0];
  const float* Wih0 = (const float*)d_in[1];
  const float* Whh0 = (const float*)d_in[2];
  const float* bih0 = (const float*)d_in[3];
  const float* bhh0 = (const float*)d_in[4];
  const float* Wih1 = (const float*)d_in[5];
  const float* Whh1 = (const float*)d_in[6];
  const float* bih1 = (const float*)d_in[7];
  const float* bhh1 = (const float*)d_in[8];
  const float* Wfc  = (const float*)d_in[9];
  const float* bfc  = (const float*)d_in[10];
  float* out = (float*)d_out;

  char* ws = (char*)d_ws;
  f16*   W0r   = (f16*)(ws + 0);          // 4096*1536*2 = 12,582,912
  f16*   W1r   = (f16*)(ws + 12582912);   // 4096*2048*2 = 16,777,216
  f16*   Wfc16 = (f16*)(ws + 29360128);   // 131,072
  float* b0r   = (float*)(ws + 29491200); // 16,384
  float* b1r   = (float*)(ws + 29507584); // 16,384
  f16*   x16   = (f16*)(ws + 29523968);   // 33,554,432
  f16*   h1all = (f16*)(ws + 63078400);   // 67,108,864
  f16*   h0b0  = (f16*)(ws + 130187264);  // 131,072
  f16*   h0b1  = (f16*)(ws + 130318336);
  f16*   h1b0  = (f16*)(ws + 130449408);
  f16*   h1b1  = (f16*)(ws + 130580480);
  float* c0    = (float*)(ws + 130711552); // 262,144
  float* c1    = (float*)(ws + 130973696); // end = 131,235,840

  k_conv_x<<<32768, 128, 0, stream>>>(x, x16);
  k_conv_w<<<4096, 256, 0, stream>>>(Wih0, Whh0, bih0, bhh0, W0r, b0r, 512);
  k_conv_w<<<4096, 256, 0, stream>>>(Wih1, Whh1, bih1, bhh1, W1r, b1r, 1024);
  k_conv_wfc<<<256, 256, 0, stream>>>(Wfc, Wfc16);
  hipMemsetAsync(ws + 130187264, 0, 1048576, stream);  // zero h/c states

  for (int t = 0; t <= 512; ++t)
    k_step<<<256, 512, 0, stream>>>(x16, W0r, b0r, W1r, b1r,
                                    h0b0, h0b1, h1b0, h1b1, c0, c1, h1all, t);

  k_fc<<<512, 512, 0, stream>>>(h1all, Wfc16, bfc, out);
}